// Round 1
// 230.875 us; speedup vs baseline: 1.0608x; 1.0608x over previous
//
#include <hip/hip_runtime.h>
#include <hip/hip_bf16.h>

// ---------------------------------------------------------------------------
// MultiHeadAttention fused kernel for MI355X (gfx950)
// B=8 S=4096 Q=32 H=8 D=64 IN=512 NKV=1024
// R5: BK=64 K-loop (16 barriers not 32), XOR-swizzled staging LDS
//     (conflict-free ds_write_b128 + ds_read_b128), 2-deep A-prefetch /
//     1-deep B-prefetch in named regs, __expf tail, k_detect inlined
//     (wave ballot) into each kernel.
// ---------------------------------------------------------------------------

typedef float f32x4 __attribute__((ext_vector_type(4)));
typedef short s16x8 __attribute__((ext_vector_type(8)));

__device__ __forceinline__ unsigned short f2bf(float f) {
  union { __hip_bfloat16 h; unsigned short u; } cv;
  cv.h = __float2bfloat16(f);
  return cv.u;
}
__device__ __forceinline__ float bf2f(unsigned short u) {
  union { unsigned short u; __hip_bfloat16 h; } cv;
  cv.u = u;
  return __bfloat162float(cv.h);
}
__device__ __forceinline__ float tofl(float v) { return v; }
__device__ __forceinline__ float tofl(__hip_bfloat16 v) { return __bfloat162float(v); }

__device__ __forceinline__ f32x4 mfma16(s16x8 a, s16x8 b, f32x4 c) {
  return __builtin_amdgcn_mfma_f32_16x16x32_bf16(a, b, c, 0, 0, 0);
}

// ---------------------------------------------------------------------------
// Inline dtype detection (1 = fp32, 0 = bf16). Reads 64 EVEN u16 entries of
// inputs: bf16 values have plausible exponents (~100%); fp32 arrays put
// mantissa low-halves at even u16 (~12% plausible). Uniform per wave.
// ---------------------------------------------------------------------------
__device__ __forceinline__ int detect_fp32(const unsigned short* __restrict__ in16) {
  unsigned short v = in16[2 * (threadIdx.x & 63)];
  int e = (v >> 7) & 0xFF;
  unsigned long long m = __ballot(e >= 100 && e <= 130);
  return __popcll(m) < 48 ? 1 : 0;
}

// ---------------------------------------------------------------------------
// LDS swizzles.
// Staging tiles [rows][64] bf16 (128 B row): 16B-unit index ^ (row&7).
//   -> fragment reads (16 lanes stride-128B) and chunk writes both hit all
//      8 four-bank groups with 8 lanes each = b128 issue floor, no conflicts.
// kv/v/P tiles [rows][128]: same scheme in 8-elem granules (sw_idx).
// ---------------------------------------------------------------------------
__device__ __forceinline__ unsigned short* stg(unsigned short* buf, int r, int u) {
  return buf + r * 64 + ((u ^ (r & 7)) << 3);
}
__device__ __forceinline__ const unsigned short* stgc(const unsigned short* buf, int r, int u) {
  return buf + r * 64 + ((u ^ (r & 7)) << 3);
}
__device__ __forceinline__ int sw_idx(int r, int c) {
  return r * 128 + ((((c >> 3) ^ (r & 7)) << 3) | (c & 7));
}

// 16-element (along K) register chunk, stored to LDS as bf16
template <typename T> struct RegChunk;
template <> struct RegChunk<float> {
  float4 v[4];
  __device__ __forceinline__ void load(const float* p) {
    const float4* q = reinterpret_cast<const float4*>(p);
    v[0] = q[0]; v[1] = q[1]; v[2] = q[2]; v[3] = q[3];
  }
  __device__ __forceinline__ void store(unsigned short* d) {  // contiguous (qproj)
    union { unsigned short u[16]; s16x8 w[2]; } t;
    const float* f = reinterpret_cast<const float*>(v);
#pragma unroll
    for (int i = 0; i < 16; ++i) t.u[i] = f2bf(f[i]);
    reinterpret_cast<s16x8*>(d)[0] = t.w[0];
    reinterpret_cast<s16x8*>(d)[1] = t.w[1];
  }
  __device__ __forceinline__ void store2(unsigned short* d0, unsigned short* d1) {  // swizzled
    union { unsigned short u[16]; s16x8 w[2]; } t;
    const float* f = reinterpret_cast<const float*>(v);
#pragma unroll
    for (int i = 0; i < 16; ++i) t.u[i] = f2bf(f[i]);
    *reinterpret_cast<s16x8*>(d0) = t.w[0];
    *reinterpret_cast<s16x8*>(d1) = t.w[1];
  }
};
template <> struct RegChunk<__hip_bfloat16> {
  s16x8 v[2];
  __device__ __forceinline__ void load(const __hip_bfloat16* p) {
    const s16x8* q = reinterpret_cast<const s16x8*>(p);
    v[0] = q[0]; v[1] = q[1];
  }
  __device__ __forceinline__ void store(unsigned short* d) {
    reinterpret_cast<s16x8*>(d)[0] = v[0];
    reinterpret_cast<s16x8*>(d)[1] = v[1];
  }
  __device__ __forceinline__ void store2(unsigned short* d0, unsigned short* d1) {
    *reinterpret_cast<s16x8*>(d0) = v[0];
    *reinterpret_cast<s16x8*>(d1) = v[1];
  }
};

// ---------------------------------------------------------------------------
// q projection as MFMA GEMM: qws[256][512] = queries[256][512] @ Wq^T + bq
// grid (2 Mtiles, 4 Ntiles), 256 thr, 128x128 tile, BK=32. (unchanged R4 body)
// ---------------------------------------------------------------------------
template <typename T>
__device__ __forceinline__ void qproj_body(const T* __restrict__ queries,
                                           const T* __restrict__ Wq,
                                           const T* __restrict__ bq,
                                           unsigned short* __restrict__ qws,
                                           unsigned short* Abuf, unsigned short* Bbuf) {
  const int Mt = blockIdx.x, Nt = blockIdx.y;
  const int tid = threadIdx.x;
  const int w = tid >> 6, l = tid & 63;
  const int quad = l >> 4, l16 = l & 15;
  const int wr = (w >> 1) * 64, wc = (w & 1) * 64;

  const int r_st = tid >> 1;
  const int kk_st = (tid & 1) * 16;
  const T* Asrc = queries + ((size_t)(Mt * 128 + r_st)) * 512 + kk_st;
  const T* Bsrc = Wq + ((size_t)(Nt * 128 + r_st)) * 512 + kk_st;

  const f32x4 zero4 = {0.f, 0.f, 0.f, 0.f};
  f32x4 acc[4][4];
#pragma unroll
  for (int i = 0; i < 4; ++i)
#pragma unroll
    for (int j = 0; j < 4; ++j) acc[i][j] = zero4;

  RegChunk<T> ra, rb;
  ra.load(Asrc);
  rb.load(Bsrc);
  for (int k0 = 0; k0 < 512; k0 += 32) {
    __syncthreads();
    ra.store(&Abuf[r_st * 32 + kk_st]);
    rb.store(&Bbuf[r_st * 32 + kk_st]);
    if (k0 + 32 < 512) {
      ra.load(Asrc + k0 + 32);
      rb.load(Bsrc + k0 + 32);
    }
    __syncthreads();
    s16x8 af[4], bfr[4];
#pragma unroll
    for (int i = 0; i < 4; ++i)
      af[i] = *reinterpret_cast<const s16x8*>(&Abuf[(wr + i * 16 + l16) * 32 + quad * 8]);
#pragma unroll
    for (int j = 0; j < 4; ++j)
      bfr[j] = *reinterpret_cast<const s16x8*>(&Bbuf[(wc + j * 16 + l16) * 32 + quad * 8]);
#pragma unroll
    for (int i = 0; i < 4; ++i)
#pragma unroll
      for (int j = 0; j < 4; ++j) acc[i][j] = mfma16(af[i], bfr[j], acc[i][j]);
  }

#pragma unroll
  for (int j = 0; j < 4; ++j) {
    float bb = tofl(bq[Nt * 128 + wc + j * 16 + l16]);
#pragma unroll
    for (int i = 0; i < 4; ++i)
#pragma unroll
      for (int rg = 0; rg < 4; ++rg) {
        int row = Mt * 128 + wr + i * 16 + quad * 4 + rg;
        int col = Nt * 128 + wc + j * 16 + l16;
        qws[(size_t)row * 512 + col] = f2bf(acc[i][j][rg] + bb);
      }
  }
}

__global__ __launch_bounds__(256) void k_qproj(const void* queries, const void* Wq,
                                               const void* bq, unsigned short* qws,
                                               const unsigned short* __restrict__ det) {
  __shared__ unsigned short Abuf[128 * 32];
  __shared__ unsigned short Bbuf[128 * 32];
  if (detect_fp32(det))
    qproj_body<float>((const float*)queries, (const float*)Wq, (const float*)bq, qws, Abuf,
                      Bbuf);
  else
    qproj_body<__hip_bfloat16>((const __hip_bfloat16*)queries, (const __hip_bfloat16*)Wq,
                               (const __hip_bfloat16*)bq, qws, Abuf, Bbuf);
}

// ---------------------------------------------------------------------------
// Fused kernel. Grid (32 s-tiles, 8 batches, 4 head-pairs), 512 threads.
// ONE BK=64 K-loop computes K-block (128x128) and V-block (128x128): waves
// 0-3 own K quadrants, 4-7 own V quadrants. Every thread stages 1 A-chunk +
// 2 B-chunks per phase into swizzled LDS. Then u-GEMM -> P -> den,
// num-GEMM -> atomics.
// ---------------------------------------------------------------------------
template <typename T>
__device__ __forceinline__ void fused_body(
    const T* __restrict__ inputs, const T* __restrict__ masks,
    const T* __restrict__ Wkv, const T* __restrict__ bkv,
    const unsigned short* __restrict__ qws,
    float* __restrict__ num, float* __restrict__ den,
    unsigned short* Abuf, unsigned short* Bbuf,
    unsigned short* kvbuf, unsigned short* vbuf, unsigned short* Pbuf) {
  const int stile = blockIdx.x;  // 0..31
  const int b = blockIdx.y;      // 0..7
  const int hp = blockIdx.z;     // 0..3
  const int s0 = stile * 128;
  const int tid = threadIdx.x;
  const int w = tid >> 6;        // 0..7
  const int l = tid & 63;
  const int quad = l >> 4;
  const int l16 = l & 15;
  const int which = w >> 2;           // 0 = K-output waves, 1 = V
  const int wr = ((w >> 1) & 1) * 64;
  const int wc = (w & 1) * 64;

  const f32x4 zero4 = {0.f, 0.f, 0.f, 0.f};
  f32x4 acc[4][4];
#pragma unroll
  for (int i = 0; i < 4; ++i)
#pragma unroll
    for (int j = 0; j < 4; ++j) acc[i][j] = zero4;

  // staging mapping: thread -> (row sr, chunk-col sc) ; 1 A + 2 B chunks
  const int sr = tid >> 2;  // 0..127
  const int sc = tid & 3;   // 16-elem chunk within 64-wide K-slice
  const T* Asrc = inputs + ((size_t)(b * 4096 + s0 + sr)) * 512 + sc * 16;
  const T* BKs = Wkv + ((size_t)(hp * 128 + sr)) * 512 + sc * 16;
  const T* BVs = Wkv + ((size_t)(512 + hp * 128 + sr)) * 512 + sc * 16;
  unsigned short* ad0 = stg(Abuf, sr, sc * 2);
  unsigned short* ad1 = stg(Abuf, sr, sc * 2 + 1);
  unsigned short* bk0 = stg(Bbuf, sr, sc * 2);
  unsigned short* bk1 = stg(Bbuf, sr, sc * 2 + 1);
  unsigned short* bv0 = stg(Bbuf, 128 + sr, sc * 2);
  unsigned short* bv1 = stg(Bbuf, 128 + sr, sc * 2 + 1);

  // 2-deep A prefetch (HBM-streamed), 1-deep B prefetch (Wkv is L2-hot).
  // Named regs (no runtime-indexed arrays -> no scratch).
  RegChunk<T> ra0, ra1, rbk, rbv;
  ra0.load(Asrc);
  ra1.load(Asrc + 64);
  rbk.load(BKs);
  rbv.load(BVs);

#pragma unroll
  for (int it2 = 0; it2 < 4; ++it2) {
#pragma unroll
    for (int ph = 0; ph < 2; ++ph) {
      const int it = it2 * 2 + ph;
      RegChunk<T>& ra = ph ? ra1 : ra0;
      __syncthreads();  // staging buffers free
      ra.store2(ad0, ad1);
      rbk.store2(bk0, bk1);
      rbv.store2(bv0, bv1);
      if (it < 6) ra.load(Asrc + (it + 2) * 64);
      if (it < 7) {
        rbk.load(BKs + (it + 1) * 64);
        rbv.load(BVs + (it + 1) * 64);
      }
      __syncthreads();  // staging visible
#pragma unroll
      for (int kk2 = 0; kk2 < 2; ++kk2) {
        s16x8 af[4], bfr[4];
#pragma unroll
        for (int i = 0; i < 4; ++i)
          af[i] = *reinterpret_cast<const s16x8*>(
              stgc(Abuf, wr + i * 16 + l16, kk2 * 4 + quad));
#pragma unroll
        for (int j = 0; j < 4; ++j)
          bfr[j] = *reinterpret_cast<const s16x8*>(
              stgc(Bbuf, which * 128 + wc + j * 16 + l16, kk2 * 4 + quad));
#pragma unroll
        for (int i = 0; i < 4; ++i)
#pragma unroll
          for (int j = 0; j < 4; ++j) acc[i][j] = mfma16(af[i], bfr[j], acc[i][j]);
      }
    }
  }

  // spill acc(+bias) to kvbuf (K, [s][c]) / vbuf (V, [c][s] transposed)
#pragma unroll
  for (int j = 0; j < 4; ++j) {
    float bb = tofl(bkv[which * 512 + hp * 128 + wc + j * 16 + l16]);
#pragma unroll
    for (int i = 0; i < 4; ++i)
#pragma unroll
      for (int rg = 0; rg < 4; ++rg) {
        int sl = wr + i * 16 + quad * 4 + rg;  // s-row (local)
        int c = wc + j * 16 + l16;             // kv col (local, = d)
        unsigned short bv = f2bf(acc[i][j][rg] + bb);
        if (which == 0)
          kvbuf[sw_idx(sl, c)] = bv;
        else
          vbuf[sw_idx(c, sl)] = bv;
      }
  }
  __syncthreads();

  // ---- u-GEMM: u[2h][32q][128s]; wave -> (hh, mt, s-half) ----
  const int hh = w >> 2, mt = (w >> 1) & 1, sh = w & 1;
  {
    f32x4 ua[4];
#pragma unroll
    for (int j = 0; j < 4; ++j) ua[j] = zero4;
#pragma unroll
    for (int kk = 0; kk < 2; ++kk) {
      s16x8 aq = *reinterpret_cast<const s16x8*>(
          qws + ((size_t)(b * 32 + mt * 16 + l16)) * 512 + hp * 128 + hh * 64 + kk * 32 +
          quad * 8);
#pragma unroll
      for (int j = 0; j < 4; ++j) {
        s16x8 bk = *reinterpret_cast<const s16x8*>(
            &kvbuf[sw_idx(sh * 64 + j * 16 + l16, hh * 64 + kk * 32 + quad * 8)]);
        ua[j] = mfma16(aq, bk, ua[j]);
      }
    }
    const float scale = 0.044194173824159216f;  // 1/sqrt(512)
    float dsum[4] = {0.f, 0.f, 0.f, 0.f};
#pragma unroll
    for (int j = 0; j < 4; ++j) {
      int scol = sh * 64 + j * 16 + l16;
      float mask = tofl(masks[(size_t)b * 4096 + s0 + scol]);
#pragma unroll
      for (int rg = 0; rg < 4; ++rg) {
        int qrow = mt * 16 + quad * 4 + rg;
        float uv = ua[j][rg] * scale;
        // elu: for uv<=0, expf(uv)-1 in (-1,0] -> lower clip at -15 is dead
        float e = uv > 0.f ? uv : (__expf(uv) - 1.f);
        e = fminf(e, 15.f);
        float p = __expf(e) * mask;
        unsigned short pu = f2bf(p);
        Pbuf[sw_idx(hh * 32 + qrow, scol)] = pu;
        dsum[rg] += bf2f(pu);  // sum the ROUNDED value num-GEMM will use
      }
    }
    // den: shuffle-reduce the 16 lanes of each quad; both s-halves atomicAdd
#pragma unroll
    for (int rg = 0; rg < 4; ++rg) {
      float s = dsum[rg];
      s += __shfl_xor(s, 1);
      s += __shfl_xor(s, 2);
      s += __shfl_xor(s, 4);
      s += __shfl_xor(s, 8);
      if (l16 == 0) {
        int qrow = mt * 16 + quad * 4 + rg;
        atomicAdd(&den[((size_t)(b * 32 + qrow)) * 8 + hp * 2 + hh], s);
      }
    }
  }
  __syncthreads();  // Pbuf complete

  // ---- num-GEMM: num[2h][32q][64d]; wave -> (hh, mt, d-half) ----
  {
    const int dh = w & 1;
    f32x4 na[2];
    na[0] = zero4;
    na[1] = zero4;
#pragma unroll
    for (int kk = 0; kk < 4; ++kk) {
      s16x8 ap = *reinterpret_cast<const s16x8*>(
          &Pbuf[sw_idx(hh * 32 + mt * 16 + l16, kk * 32 + quad * 8)]);
#pragma unroll
      for (int jj = 0; jj < 2; ++jj) {
        int j = dh * 2 + jj;
        s16x8 bv = *reinterpret_cast<const s16x8*>(
            &vbuf[sw_idx(hh * 64 + j * 16 + l16, kk * 32 + quad * 8)]);
        na[jj] = mfma16(ap, bv, na[jj]);
      }
    }
    const int h = hp * 2 + hh;
#pragma unroll
    for (int jj = 0; jj < 2; ++jj) {
      int d = (dh * 2 + jj) * 16 + l16;
#pragma unroll
      for (int rg = 0; rg < 4; ++rg) {
        int qrow = mt * 16 + quad * 4 + rg;
        atomicAdd(&num[(((size_t)(b * 32 + qrow)) * 8 + h) * 64 + d], na[jj][rg]);
      }
    }
  }
}

__global__ __launch_bounds__(512, 2) void k_fused(const void* inputs, const void* masks,
                                                  const void* Wkv, const void* bkv,
                                                  const unsigned short* __restrict__ qws,
                                                  float* __restrict__ num,
                                                  float* __restrict__ den) {
  __shared__ unsigned short Abuf[128 * 64];     // 16 KiB  inputs chunk, swizzled
  __shared__ unsigned short Bbuf[256 * 64];     // 32 KiB  Wkv chunk (K+V), swizzled
  __shared__ unsigned short kvbuf[128 * 128];   // 32 KiB  K [s][c] swizzled
  __shared__ unsigned short vbuf[128 * 128];    // 32 KiB  V [c][s] swizzled
  __shared__ unsigned short Pbuf[64 * 128];     // 16 KiB  P [2h*32q][s] swizzled
  if (detect_fp32((const unsigned short*)inputs))
    fused_body<float>((const float*)inputs, (const float*)masks, (const float*)Wkv,
                      (const float*)bkv, qws, num, den, Abuf, Bbuf, kvbuf, vbuf, Pbuf);
  else
    fused_body<__hip_bfloat16>((const __hip_bfloat16*)inputs, (const __hip_bfloat16*)masks,
                               (const __hip_bfloat16*)Wkv, (const __hip_bfloat16*)bkv, qws,
                               num, den, Abuf, Bbuf, kvbuf, vbuf, Pbuf);
}

// ---------------------------------------------------------------------------
__global__ __launch_bounds__(256) void k_div(const float* __restrict__ num,
                                             const float* __restrict__ den, void* out,
                                             const unsigned short* __restrict__ det) {
  int i = blockIdx.x * 256 + threadIdx.x;
  float v = num[i] / den[i >> 6];
  if (detect_fp32(det))
    ((float*)out)[i] = v;
  else
    ((__hip_bfloat16*)out)[i] = __float2bfloat16(v);
}

// ---------------------------------------------------------------------------
extern "C" void kernel_launch(void* const* d_in, const int* in_sizes, int n_in,
                              void* d_out, int out_size, void* d_ws, size_t ws_size,
                              hipStream_t stream) {
  // d_in: 0 inputs, 1 queries, 2 masks, 3 Wkv, 4 bkv, 5 Wq, 6 bq
  // ws: [1024] den 2048 f32 ; [16384] num 131072 f32 ;
  //     [540672] qws 131072 u16 -> 802816 bytes
  if (ws_size < 802816) return;
  char* ws = (char*)d_ws;
  float* den = (float*)(ws + 1024);
  float* num = (float*)(ws + 16384);
  unsigned short* qws = (unsigned short*)(ws + 540672);

  hipMemsetAsync(d_ws, 0, 540672, stream);

  dim3 gq(2, 4);
  k_qproj<<<gq, 256, 0, stream>>>(d_in[1], d_in[5], d_in[6], qws,
                                  (const unsigned short*)d_in[0]);

  dim3 g2(32, 8, 4);
  k_fused<<<g2, 512, 0, stream>>>(d_in[0], d_in[2], d_in[3], d_in[4], qws, num, den);

  k_div<<<512, 256, 0, stream>>>(num, den, d_out, (const unsigned short*)d_in[0]);
}